// Round 4
// baseline (320.201 us; speedup 1.0000x reference)
//
#include <hip/hip_runtime.h>
#include <hip/hip_bf16.h>
#include <cstdint>
#include <cstddef>

// MHA B=2,S=2048,D=1024,H=16,HD=64.
// cvt(fp32->bf16) -> fused QKV GEMM (m97 global_load_lds) -> V-transpose ->
// flash attn (direct-global K/V frags; LDS only for P, barrier-bracketed) -> O GEMM.
//
// R3 lesson: cross-lane LDS write->read MUST be bracketed by __syncthreads().
// Per-lane-disjoint DS addresses license compiler reordering across iterations;
// round 3's barrier-free version diverged under graph replay.

#define B_  2
#define S_  2048
#define D_  1024
#define H_  16
#define HD_ 64

typedef __bf16 bf16x8 __attribute__((ext_vector_type(8)));
typedef __bf16 bf16x4 __attribute__((ext_vector_type(4)));
typedef float  f32x4  __attribute__((ext_vector_type(4)));

// ---- async global->LDS, 16B per lane. LDS dest must be wave-uniform base;
// HW adds lane*16 (guide §5 m97/m104).
__device__ __forceinline__ void async16(const __bf16* g, const __bf16* l) {
  __builtin_amdgcn_global_load_lds(
      (const __attribute__((address_space(1))) void*)(uintptr_t)g,
      (__attribute__((address_space(3))) void*)(uint32_t)(uintptr_t)l,
      16, 0, 0);
}

// ---------------- fp32 -> bf16 convert (x + 4 weights) ----------------
__global__ __launch_bounds__(256) void cvt_all(const float* __restrict__ x,
    const float* __restrict__ wq, const float* __restrict__ wk,
    const float* __restrict__ wv, const float* __restrict__ wo,
    __bf16* __restrict__ xb, __bf16* __restrict__ wqb, __bf16* __restrict__ wkb,
    __bf16* __restrict__ wvb, __bf16* __restrict__ wob) {
  const int sel = blockIdx.y;
  const float* src; __bf16* dst; int n;
  if      (sel == 0) { src = x;  dst = xb;  n = B_ * S_ * D_; }
  else if (sel == 1) { src = wq; dst = wqb; n = D_ * D_; }
  else if (sel == 2) { src = wk; dst = wkb; n = D_ * D_; }
  else if (sel == 3) { src = wv; dst = wvb; n = D_ * D_; }
  else               { src = wo; dst = wob; n = D_ * D_; }
  for (int i = blockIdx.x * 256 + threadIdx.x; i * 4 < n; i += gridDim.x * 256) {
    const float4 v = *(const float4*)(src + (size_t)i * 4);
    bf16x4 o;
    o[0] = (__bf16)v.x; o[1] = (__bf16)v.y; o[2] = (__bf16)v.z; o[3] = (__bf16)v.w;
    *(bf16x4*)(dst + (size_t)i * 4) = o;
  }
}

// ---------------- m97-style GEMM body: C[M][N] = A[M][K] * B[N][K]^T ----------------
template <typename TC>
__device__ __forceinline__ void gemm97_body(const __bf16* __restrict__ A,
                                            const __bf16* __restrict__ Bm,
                                            TC* __restrict__ C,
                                            const int m0, const int n0,
                                            const int N, const int K) {
  __shared__ __align__(16) __bf16 As[128 * 64];  // unpadded: global_load_lds order
  __shared__ __align__(16) __bf16 Bs[128 * 64];
  const int tid  = threadIdx.x, lane = tid & 63, wave = tid >> 6;
  const int l15  = lane & 15,   quad = lane >> 4;
  const int wr   = wave >> 1,   wc   = wave & 1;
  const int ebase = wave * 2048 + lane * 8;  // elem offset this lane covers (chunk 0)

  f32x4 acc[4][4] = {};
  for (int k0 = 0; k0 < K; k0 += 64) {
#pragma unroll
    for (int i = 0; i < 4; ++i) {
      const int e = ebase + i * 512;
      const int row = e >> 6, col = e & 63;
      async16(A  + (size_t)(m0 + row) * K + k0 + col, As + (wave * 4 + i) * 512);
      async16(Bm + (size_t)(n0 + row) * K + k0 + col, Bs + (wave * 4 + i) * 512);
    }
    __syncthreads();
#pragma unroll
    for (int kk = 0; kk < 2; ++kk) {
      bf16x8 af[4], bfv[4];
#pragma unroll
      for (int rt = 0; rt < 4; ++rt)
        af[rt] = *(const bf16x8*)(As + (wr * 64 + rt * 16 + l15) * 64 + kk * 32 + quad * 8);
#pragma unroll
      for (int ct = 0; ct < 4; ++ct)
        bfv[ct] = *(const bf16x8*)(Bs + (wc * 64 + ct * 16 + l15) * 64 + kk * 32 + quad * 8);
#pragma unroll
      for (int rt = 0; rt < 4; ++rt)
#pragma unroll
        for (int ct = 0; ct < 4; ++ct)
          acc[rt][ct] = __builtin_amdgcn_mfma_f32_16x16x32_bf16(af[rt], bfv[ct], acc[rt][ct], 0, 0, 0);
    }
    __syncthreads();
  }
#pragma unroll
  for (int rt = 0; rt < 4; ++rt)
#pragma unroll
    for (int ct = 0; ct < 4; ++ct)
#pragma unroll
      for (int r = 0; r < 4; ++r) {
        const int row = m0 + wr * 64 + rt * 16 + quad * 4 + r;
        const int col = n0 + wc * 64 + ct * 16 + l15;
        C[(size_t)row * N + col] = (TC)acc[rt][ct][r];
      }
}

__global__ __launch_bounds__(256) void qkv_gemm(const __bf16* __restrict__ xb,
                                                const __bf16* __restrict__ wq,
                                                const __bf16* __restrict__ wk,
                                                const __bf16* __restrict__ wv,
                                                __bf16* __restrict__ qkv) {
  const int sel = blockIdx.x >> 3;  // 0..2 -> Q,K,V
  const __bf16* Bm = (sel == 0) ? wq : (sel == 1) ? wk : wv;
  __bf16* C = qkv + (size_t)sel * ((size_t)B_ * S_ * D_);
  gemm97_body<__bf16>(xb, Bm, C, blockIdx.y * 128, (blockIdx.x & 7) * 128, D_, D_);
}

__global__ __launch_bounds__(256) void o_gemm(const __bf16* __restrict__ cb,
                                              const __bf16* __restrict__ wo,
                                              float* __restrict__ out) {
  gemm97_body<float>(cb, wo, out, blockIdx.y * 128, blockIdx.x * 128, D_, D_);
}

// ---------------- V transpose: vb[B*S][D] -> vt[(b*16+h)*64+hd][S] ----------------
__global__ __launch_bounds__(256) void vtrans(const __bf16* __restrict__ vb,
                                              __bf16* __restrict__ vt) {
  __shared__ __bf16 tbuf[64][72];
  const int tid = threadIdx.x;
  const int s0 = blockIdx.x * 64, bh = blockIdx.y;
  const int b = bh >> 4, h = bh & 15;
  const __bf16* src = vb + ((size_t)b * S_ + s0) * D_ + h * HD_;
#pragma unroll
  for (int i = 0; i < 2; ++i) {
    const int r = i * 32 + (tid >> 3), c8 = (tid & 7) * 8;
    *(bf16x8*)(&tbuf[r][c8]) = *(const bf16x8*)(src + (size_t)r * D_ + c8);
  }
  __syncthreads();
  __bf16* dst = vt + (size_t)bh * HD_ * S_ + s0;
#pragma unroll
  for (int i = 0; i < 2; ++i) {
    const int hd = i * 32 + (tid >> 3), sc = (tid & 7) * 8;
    bf16x8 v;
#pragma unroll
    for (int j = 0; j < 8; ++j) v[j] = tbuf[sc + j][hd];
    *(bf16x8*)(dst + (size_t)hd * S_ + sc) = v;
  }
}

// ---------------- flash attention, S^T form, direct-global K/V ----------------
// Block: 128 q-rows of one (b,h); 4 waves x 32 q (t=0,1). KV tile = 128 keys.
// K frags (A-op) and Vt frags (B-op) load DIRECTLY from global (16B contiguous,
// L1/L2-served). Only P round-trips through per-wave LDS; the write->read is
// bracketed by __syncthreads() (loop-top + post-write) — R3 lesson.
__global__ __launch_bounds__(256) void attn4(const __bf16* __restrict__ Q,
                                             const __bf16* __restrict__ K,
                                             const __bf16* __restrict__ Vt,
                                             const float* __restrict__ mask,
                                             __bf16* __restrict__ O) {
  constexpr int LPS = 136;                       // 272 B rows: 2-way banks (free)
  __shared__ __align__(16) __bf16 ps[128 * LPS]; // 34.8 KB total LDS

  const int tid  = threadIdx.x, lane = tid & 63, wave = tid >> 6;
  const int l15  = lane & 15,   quad = lane >> 4;
  const int b = blockIdx.z, h = blockIdx.y, q0 = blockIdx.x * 128;
  const size_t base   = (size_t)b * S_ * D_ + h * HD_;
  const size_t vtbase = (size_t)(b * H_ + h) * HD_ * S_;
  const float* mrow   = mask + (size_t)b * S_;
  const int qw = q0 + wave * 32;
  const float L2E = 1.442695041f;

  // Q fragments (B-operand: lane n=l15 -> q row, k = kb*32+quad*8+j)
  bf16x8 qf[2][2];
#pragma unroll
  for (int t = 0; t < 2; ++t)
#pragma unroll
    for (int kb = 0; kb < 2; ++kb)
      qf[t][kb] = *(const bf16x8*)(Q + base + (size_t)(qw + t * 16 + l15) * D_ + kb * 32 + quad * 8);

  float m_run[2] = {-1e30f, -1e30f}, l_run[2] = {0.f, 0.f};
  f32x4 oacc[2][4] = {};

  for (int t0 = 0; t0 < S_; t0 += 128) {
    __syncthreads();  // orders prior iter's ps reads before this iter's writes
    // ---- S^T tiles: D[m=key][n=q]; A = K rows direct from global ----
    f32x4 sacc[8][2] = {};
#pragma unroll
    for (int kti = 0; kti < 8; ++kti) {
      const __bf16* kp = K + base + (size_t)(t0 + kti * 16 + l15) * D_ + quad * 8;
      const bf16x8 a0 = *(const bf16x8*)(kp);
      const bf16x8 a1 = *(const bf16x8*)(kp + 32);
#pragma unroll
      for (int t = 0; t < 2; ++t) {
        sacc[kti][t] = __builtin_amdgcn_mfma_f32_16x16x32_bf16(a0, qf[t][0], sacc[kti][t], 0, 0, 0);
        sacc[kti][t] = __builtin_amdgcn_mfma_f32_16x16x32_bf16(a1, qf[t][1], sacc[kti][t], 0, 0, 0);
      }
    }
    // scale + additive mask (per-key -> per acc row; quad-uniform 16B load)
#pragma unroll
    for (int kti = 0; kti < 8; ++kti) {
      const f32x4 mv = *(const f32x4*)(mrow + t0 + kti * 16 + quad * 4);
#pragma unroll
      for (int t = 0; t < 2; ++t)
#pragma unroll
        for (int r = 0; r < 4; ++r)
          sacc[kti][t][r] = fmaf(sacc[kti][t][r], 0.125f, mv[r]);
    }
    // online softmax: per-lane over 32 keys, then quad hops (16,32)
    float mnew[2], alpha[2], tsum[2], ml2[2];
#pragma unroll
    for (int t = 0; t < 2; ++t) {
      float tm = -1e30f;
#pragma unroll
      for (int kti = 0; kti < 8; ++kti)
#pragma unroll
        for (int r = 0; r < 4; ++r) tm = fmaxf(tm, sacc[kti][t][r]);
      tm = fmaxf(tm, __shfl_xor(tm, 16));
      tm = fmaxf(tm, __shfl_xor(tm, 32));
      mnew[t]  = fmaxf(m_run[t], tm);
      alpha[t] = __builtin_amdgcn_exp2f((m_run[t] - mnew[t]) * L2E);
      m_run[t] = mnew[t];
      ml2[t]   = mnew[t] * L2E;
      tsum[t]  = 0.f;
    }
    // P = exp2(s*L2E - m*L2E), write P[q][key] (b64, 2-way banks = free)
#pragma unroll
    for (int t = 0; t < 2; ++t) {
      __bf16* pr = ps + (size_t)(wave * 32 + t * 16 + l15) * LPS + quad * 4;
#pragma unroll
      for (int kti = 0; kti < 8; ++kti) {
        bf16x4 pv;
#pragma unroll
        for (int r = 0; r < 4; ++r) {
          const float p = __builtin_amdgcn_exp2f(fmaf(sacc[kti][t][r], L2E, -ml2[t]));
          tsum[t] += p;
          pv[r] = (__bf16)p;
        }
        *(bf16x4*)(pr + kti * 16) = pv;
      }
    }
#pragma unroll
    for (int t = 0; t < 2; ++t) {
      float ts = tsum[t];
      ts += __shfl_xor(ts, 16);
      ts += __shfl_xor(ts, 32);
      l_run[t] = l_run[t] * alpha[t] + ts;
      // rescale O-acc: acc rows are q=quad*4+r, alpha lives at lane l15=q
#pragma unroll
      for (int r = 0; r < 4; ++r) {
        const float aR = __shfl(alpha[t], quad * 4 + r);
#pragma unroll
        for (int nt = 0; nt < 4; ++nt) oacc[t][nt][r] *= aR;
      }
    }
    __syncthreads();  // P writes ordered before A-layout reads (R3 lesson)
    // ---- O += P·V: A = ps rows, B = Vt rows direct from global ----
#pragma unroll
    for (int kb = 0; kb < 4; ++kb) {
      bf16x8 pa[2];
#pragma unroll
      for (int t = 0; t < 2; ++t)
        pa[t] = *(const bf16x8*)(ps + (size_t)(wave * 32 + t * 16 + l15) * LPS + kb * 32 + quad * 8);
#pragma unroll
      for (int nt = 0; nt < 4; ++nt) {
        const bf16x8 vf = *(const bf16x8*)(Vt + vtbase + (size_t)(nt * 16 + l15) * S_ + t0 + kb * 32 + quad * 8);
#pragma unroll
        for (int t = 0; t < 2; ++t)
          oacc[t][nt] = __builtin_amdgcn_mfma_f32_16x16x32_bf16(pa[t], vf, oacc[t][nt], 0, 0, 0);
      }
    }
  }
  // epilogue: divide by l (broadcast per acc row), store ctx
#pragma unroll
  for (int t = 0; t < 2; ++t)
#pragma unroll
    for (int r = 0; r < 4; ++r) {
      const float lR  = __shfl(l_run[t], quad * 4 + r);
      const float inv = 1.0f / lR;
      const int row = qw + t * 16 + quad * 4 + r;
#pragma unroll
      for (int nt = 0; nt < 4; ++nt)
        O[base + (size_t)row * D_ + nt * 16 + l15] = (__bf16)(oacc[t][nt][r] * inv);
    }
}

extern "C" void kernel_launch(void* const* d_in, const int* in_sizes, int n_in,
                              void* d_out, int out_size, void* d_ws, size_t ws_size,
                              hipStream_t stream) {
  const float* x    = (const float*)d_in[0];
  const float* mask = (const float*)d_in[1];
  const float* Wq   = (const float*)d_in[2];
  const float* Wk   = (const float*)d_in[3];
  const float* Wv   = (const float*)d_in[4];
  const float* Wo   = (const float*)d_in[5];

  char* ws = (char*)d_ws;
  const size_t MB = 1ull << 20;
  const size_t NT = (size_t)B_ * S_ * D_;  // 4M elems, 8 MB bf16
  __bf16* xb  = (__bf16*)(ws);             // 8 MB; reused as vtb after qkv_gemm
  __bf16* wqb = (__bf16*)(ws + 8 * MB);
  __bf16* wkb = (__bf16*)(ws + 10 * MB);
  __bf16* wvb = (__bf16*)(ws + 12 * MB);
  __bf16* wob = (__bf16*)(ws + 14 * MB);
  __bf16* qkv = (__bf16*)(ws + 16 * MB);   // 24 MB
  __bf16* qb  = qkv;
  __bf16* kb  = qkv + NT;
  __bf16* vb  = qkv + 2 * NT;
  __bf16* vtb = xb;   // x consumed by qkv_gemm before vtrans writes (stream order)
  __bf16* cb  = vb;   // v consumed by vtrans before attn writes ctx

  cvt_all<<<dim3(1024, 5), 256, 0, stream>>>(x, Wq, Wk, Wv, Wo, xb, wqb, wkb, wvb, wob);
  qkv_gemm<<<dim3(24, 32), 256, 0, stream>>>(xb, wqb, wkb, wvb, qkv);
  vtrans<<<dim3(32, 32), 256, 0, stream>>>(vb, vtb);
  attn4<<<dim3(S_ / 128, H_, B_), 256, 0, stream>>>(qb, kb, vtb, mask, cb);
  o_gemm<<<dim3(8, 32), 256, 0, stream>>>(cb, wob, (float*)d_out);
}